// Round 20
// baseline (473.208 us; speedup 1.0000x reference)
//
#include <hip/hip_runtime.h>
#include <math.h>

#define I_IMG 3
#define S_SEQ 64
#define C_CH  512
#define H_IN  18
#define W_IN  18
#define HW    324
#define OH 19
#define OW 19
#define NPIX 361
#define FT 16
#define NITER 5
#define RPW 24            // tr rp row stride
#define CVS 32            // uint slots per convert block
#define CVP 162           // pixels per convert block
#define SPL 336           // S plane length (21 tiles x 16)
#define BPL 352           // featB padded plane length (11 x 32)
#define ASTR 360          // A-lds row stride (ushorts): 2-way-free banks

typedef unsigned int uint;
typedef unsigned short ushort;
typedef float f32x4 __attribute__((ext_vector_type(4)));
typedef short s16x8 __attribute__((ext_vector_type(8)));

__device__ inline float blk_reduce(float v, float* tmp) {
  #pragma unroll
  for (int o = 32; o > 0; o >>= 1) v += __shfl_down(v, o, 64);
  int lane = threadIdx.x & 63;
  int w = threadIdx.x >> 6;
  if (lane == 0) tmp[w] = v;
  __syncthreads();
  float r = 0.f;
  if (threadIdx.x == 0) {
    int nw = (blockDim.x + 63) >> 6;
    for (int k = 0; k < nw; ++k) r += tmp[k];
  }
  return r;
}

__device__ inline uint pack_bf2(float lo, float hi) {  // RNE f32x2 -> packed bf16x2
  uint ul = __float_as_uint(lo);
  uint uh = __float_as_uint(hi);
  ul = (ul + 0x7fffu + ((ul >> 16) & 1u)) >> 16;
  uh = (uh + 0x7fffu + ((uh >> 16) & 1u)) & 0xffff0000u;
  return ul | uh;
}

__device__ inline uint pack_bf2_adj(float a, float b) { // (a,b) -> bf16(a)|bf16(b)<<16
  uint ua = __float_as_uint(a);
  uint ub = __float_as_uint(b);
  ua = (ua + 0x7fffu + ((ua >> 16) & 1u)) >> 16;
  ub = (ub + 0x7fffu + ((ub >> 16) & 1u)) & 0xffff0000u;
  return ua | ub;
}

__device__ inline ushort bf16r(float f) {  // RNE f32 -> bf16
  uint u = __float_as_uint(f);
  return (ushort)((u + 0x7fffu + ((u >> 16) & 1u)) >> 16);
}

// ushort index within featT's packed channel order for natural channel c
__device__ inline int chperm(int c) { return (c < 256) ? 2 * c : 2 * (c - 256) + 1; }

// ---------------------------------------------------------------------------
// convert: feat f32 [n][c][p] -> featT packed-bf16 [n][p][k]   (fwd A operand)
//                             -> featB bf16 [n][c][352-padded] (tr  B operand)
// grid (192, 16). Stage loop coalesced; featT via swizzled LDS transpose.
// ---------------------------------------------------------------------------
__global__ __launch_bounds__(256) void convert_k(
    const float* __restrict__ feat, ushort* __restrict__ featT,
    ushort* __restrict__ featB)
{
  __shared__ uint tile[CVP * CVS];   // 20736 B
  int tid = threadIdx.x;
  int n = blockIdx.x;
  int yz = blockIdx.y;
  int k0 = (yz >> 1) * CVS;
  int p0 = (yz & 1) * CVP;
  const float* fbase = feat + (size_t)n * C_CH * HW + p0;

  for (int idx = tid; idx < CVS * 81; idx += 256) {
    int k = idx / 81, q = idx - k * 81;
    int j = k0 + k;
    float2 lo = *(const float2*)(fbase + (size_t)j * HW + 2 * q);
    float2 hi = *(const float2*)(fbase + (size_t)(j + 256) * HW + 2 * q);
    uint b = (uint)(2 * q) * CVS + (uint)(k ^ (q & 31));  // XOR bank swizzle
    tile[b] = pack_bf2(lo.x, hi.x);
    tile[b + CVS] = pack_bf2(lo.y, hi.y);
    // channel-major bf16 copies for the tr GEMM (B operand)
    *(uint*)(featB + ((size_t)n * C_CH + j) * BPL + p0 + 2 * q) =
        pack_bf2_adj(lo.x, lo.y);
    *(uint*)(featB + ((size_t)n * C_CH + j + 256) * BPL + p0 + 2 * q) =
        pack_bf2_adj(hi.x, hi.y);
  }
  // zero featB plane pads (once per channel; done by the p0=162 half-blocks)
  if (yz & 1) {
    for (int idx = tid; idx < 64 * 14; idx += 256) {
      int cc = idx / 14, o = idx - cc * 14;
      int j = k0 + (cc & 31) + (cc >> 5) * 256;
      *(uint*)(featB + ((size_t)n * C_CH + j) * BPL + HW + 2 * o) = 0u;
    }
  }
  __syncthreads();

  uint* dTb = (uint*)featT + ((size_t)n * HW + p0) * (C_CH / 2) + k0;
  for (int idx = tid; idx < CVP * CVS; idx += 256) {
    int px = idx >> 5, k = idx & 31;
    dTb[(size_t)px * (C_CH / 2) + k] = tile[px * CVS + (k ^ ((px >> 1) & 31))];
  }
}

// ---------------------------------------------------------------------------
// prep: distance map -> label_map, sample_weight, a_lo, a_hi; scalars
// ---------------------------------------------------------------------------
__global__ void prep_k(const float* __restrict__ bb,
                       const float* __restrict__ label_w,
                       const float* __restrict__ mask_w,
                       const float* __restrict__ spatial_w,
                       const float* __restrict__ lsl,
                       const float* __restrict__ freg,
                       float* __restrict__ sw, float* __restrict__ lm,
                       float* __restrict__ alo, float* __restrict__ ahi,
                       float* __restrict__ scal)
{
  int n = blockIdx.x;
  int p = threadIdx.x;
  if (n == 0 && p == 0) {
    scal[0] = expf(lsl[0]);
    scal[1] = fmaxf(freg[0] * freg[0], 1e-6f);
  }
  if (p >= NPIX) return;
  float bx = bb[n * 4 + 0], by = bb[n * 4 + 1];
  float bw = bb[n * 4 + 2], bh = bb[n * 4 + 3];
  float crow = (by + bh * 0.5f) * (1.f / 16.f);
  float ccol = (bx + bw * 0.5f) * (1.f / 16.f);
  int y = p / OW, x = p - (p / OW) * OW;
  float d0 = (float)y - crow, d1 = (float)x - ccol;
  float dist = sqrtf(d0 * d0 + d1 * d1);
  float bins[5];
  #pragma unroll
  for (int b = 0; b < 4; ++b) bins[b] = fmaxf(1.f - fabsf(dist - (float)b), 0.f);
  bins[4] = fminf(fmaxf(dist - 3.f, 0.f), 1.f);
  float lmv = 0.f, mm = 0.f, sp = 0.f;
  #pragma unroll
  for (int b = 0; b < 5; ++b) {
    lmv += bins[b] * label_w[b];
    mm  += bins[b] * mask_w[b];
    sp  += bins[b] * spatial_w[b];
  }
  float tm = 1.f / (1.f + expf(-mm));
  int idx = n * NPIX + p;
  lm[idx]  = lmv;
  sw[idx]  = 0.57735026918962584f * sp;
  alo[idx] = 0.5f * (1.f - tm);
  ahi[idx] = 0.5f * (1.f + tm);
}

// ---------------------------------------------------------------------------
// wT_k: w fp32 [s][c][16] -> wTb bf16 [s][t][512] (featT channel order)
// ---------------------------------------------------------------------------
__global__ __launch_bounds__(256) void wT_k(
    const float* __restrict__ w, ushort* __restrict__ wTb)
{
  int s = blockIdx.x;
  const float4* pw = (const float4*)(w + (size_t)s * C_CH * FT);
  ushort* wb = wTb + (size_t)s * 16 * 512;
  for (int g = threadIdx.x; g < C_CH * FT / 4; g += 256) {
    int c = g >> 2, tq = (g & 3) * 4;
    float4 v = pw[g];
    int k = chperm(c);
    wb[(tq + 0) * 512 + k] = bf16r(v.x);
    wb[(tq + 1) * 512 + k] = bf16r(v.y);
    wb[(tq + 2) * 512 + k] = bf16r(v.z);
    wb[(tq + 3) * 512 + k] = bf16r(v.w);
  }
}

// ---------------------------------------------------------------------------
// mfma_fwd (R17-proven): S[n][t][p] = sum_c featT[n][p][c] * wTb[s][t][c]
// ---------------------------------------------------------------------------
__global__ __launch_bounds__(256) void mfma_fwd_k(
    const ushort* __restrict__ featT, const ushort* __restrict__ wTb,
    float* __restrict__ S)
{
  int lane = threadIdx.x & 63;
  int wv = threadIdx.x >> 6;
  int n = blockIdx.x;
  int s = n & 63;
  int mtile = blockIdx.y * 4 + wv;
  if (mtile >= 21) return;
  int mrow = lane & 15;
  int kg = lane >> 4;

  const ushort* wb = wTb + ((size_t)s * 16 + mrow) * 512 + kg * 8;
  s16x8 bfrag[16];
  #pragma unroll
  for (int k0 = 0; k0 < 16; ++k0)
    bfrag[k0] = *(const s16x8*)(wb + k0 * 32);

  int p = mtile * 16 + mrow;
  bool pvalid = p < HW;
  const ushort* fa = featT + ((size_t)n * HW + (pvalid ? p : 0)) * 512 + kg * 8;
  s16x8 zero8 = {0, 0, 0, 0, 0, 0, 0, 0};

  f32x4 acc = {0.f, 0.f, 0.f, 0.f};
  #pragma unroll
  for (int k0 = 0; k0 < 16; ++k0) {
    s16x8 afrag = pvalid ? *(const s16x8*)(fa + k0 * 32) : zero8;
    acc = __builtin_amdgcn_mfma_f32_16x16x32_bf16(afrag, bfrag[k0], acc, 0, 0, 0);
  }

  float* dst = S + ((size_t)n * 16 + mrow) * SPL + mtile * 16 + kg * 4;
  *(float4*)dst = make_float4(acc[0], acc[1], acc[2], acc[3]);
}

// ---------------------------------------------------------------------------
// mfma_tr: wgp[i][s][c][t] = sum_p A[t][p] * featB[(i,s,c)][p]
// A = R^T (bf16, built in LDS from residual plane). grid (6,64) x 256.
// blockIdx.x = i*2 + nh (channel half); wave wv covers 4 n-tiles.
// ---------------------------------------------------------------------------
__global__ __launch_bounds__(256) void mfma_tr_k(
    const ushort* __restrict__ featB, const float* __restrict__ r,
    float* __restrict__ wgp)
{
  __shared__ __align__(16) float rp[21 * RPW];
  __shared__ __align__(16) ushort Ald[16 * ASTR];
  int tid = threadIdx.x;
  int i = blockIdx.x >> 1;
  int nh = blockIdx.x & 1;
  int s = blockIdx.y;

  for (int idx = tid; idx < 21 * RPW; idx += 256) rp[idx] = 0.f;
  __syncthreads();
  for (int idx = tid; idx < NPIX; idx += 256) {
    int y = idx / OW, x = idx - y * OW;
    rp[(y + 1) * RPW + (x + 1)] = r[(size_t)(i * S_SEQ + s) * NPIX + idx];
  }
  __syncthreads();

  // A[t][p] = rp[(u+3-dy)*RPW + (v+3-dx)], t=dy*4+dx, p=u*18+v; pad zeros
  for (int idx = tid; idx < 16 * BPL; idx += 256) {
    int t = idx / BPL, pp = idx - t * BPL;
    ushort val = 0;
    if (pp < HW) {
      int u = pp / 18, vv = pp - u * 18;
      int dy = t >> 2, dx = t & 3;
      val = bf16r(rp[(u + 3 - dy) * RPW + (vv + 3 - dx)]);
    }
    Ald[t * ASTR + pp] = val;
  }
  __syncthreads();

  int lane = tid & 63, wv = tid >> 6;
  int nsub = lane & 15, kg = lane >> 4;

  // A frags (shared across this lane's 4 n-tiles)
  const ushort* arow = Ald + nsub * ASTR + kg * 8;
  s16x8 afr[11];
  #pragma unroll
  for (int ks = 0; ks < 11; ++ks)
    afr[ks] = *(const s16x8*)(arow + ks * 32);

  size_t nsbase = ((size_t)i * S_SEQ + s) * C_CH;
  #pragma unroll
  for (int j = 0; j < 4; ++j) {
    int nt = nh * 16 + wv * 4 + j;
    int c = nt * 16 + nsub;
    const ushort* bb = featB + (nsbase + c) * BPL + kg * 8;
    f32x4 acc = {0.f, 0.f, 0.f, 0.f};
    #pragma unroll
    for (int ks = 0; ks < 11; ++ks) {
      s16x8 bf = *(const s16x8*)(bb + ks * 32);
      acc = __builtin_amdgcn_mfma_f32_16x16x32_bf16(afr[ks], bf, acc, 0, 0, 0);
    }
    float* dst = wgp + (nsbase + c) * FT + kg * 4;
    *(float4*)dst = make_float4(acc[0], acc[1], acc[2], acc[3]);
  }
}

// ---------------------------------------------------------------------------
// gather scores from S planes
// ---------------------------------------------------------------------------
__device__ inline float s_gather(const float* __restrict__ Sp, int yo, int xo) {
  float sv = 0.f;
  #pragma unroll
  for (int dy = 0; dy < 4; ++dy) {
    int yi = yo + dy - 2;
    if (yi < 0 || yi >= H_IN) continue;
    #pragma unroll
    for (int dx = 0; dx < 4; ++dx) {
      int xi = xo + dx - 2;
      if (xi < 0 || xi >= W_IN) continue;
      sv += Sp[(dy * 4 + dx) * SPL + yi * W_IN + xi];
    }
  }
  return sv;
}

// ---------------------------------------------------------------------------
// combine0 (once): S -> scores + mask + residuals
// ---------------------------------------------------------------------------
__global__ __launch_bounds__(384) void combine0_k(
    const float* __restrict__ S,
    const float* __restrict__ sw, const float* __restrict__ lm,
    const float* __restrict__ alo, const float* __restrict__ ahi,
    float* __restrict__ scores,
    float* __restrict__ mask, float* __restrict__ rbuf)
{
  int n = blockIdx.x;
  int p = threadIdx.x;
  if (p >= NPIX) return;
  int yo = p / OW, xo = p - yo * OW;
  float sv = s_gather(S + (size_t)n * 16 * SPL, yo, xo);
  int idx = n * NPIX + p;
  scores[idx] = sv;
  float lo = alo[idx], hi = ahi[idx], s_w = sw[idx], l_v = lm[idx];
  float sgn = (sv > 0.f) ? 1.f : ((sv < 0.f) ? -1.f : 0.f);
  float actv = lo * fabsf(sv) + hi * sv;
  float msk = lo * sgn + hi;
  mask[idx] = msk;
  rbuf[idx] = msk * s_w * s_w * (actv - l_v);
}

// ---------------------------------------------------------------------------
// combine_wg: wg = sum_i wgp + reg*wcur (fp32) + wgTb bf16 [s][t][512];
// nump[s] = ||wg||^2
// ---------------------------------------------------------------------------
__global__ __launch_bounds__(256) void combine_wg_k(
    const float* __restrict__ wgp, const float* __restrict__ wcur,
    const float* __restrict__ scal,
    float* __restrict__ wg, ushort* __restrict__ wgTb,
    float* __restrict__ nump)
{
  __shared__ float rtmp[4];
  int s = blockIdx.x;
  int tid = threadIdx.x;
  float regv = scal[1];
  size_t base = (size_t)s * C_CH * FT;
  size_t istr = (size_t)S_SEQ * C_CH * FT;
  const float4* p0 = (const float4*)(wgp + base);
  const float4* p1 = (const float4*)(wgp + istr + base);
  const float4* p2 = (const float4*)(wgp + 2 * istr + base);
  const float4* pw = (const float4*)(wcur + base);
  float4* pg = (float4*)(wg + base);
  ushort* wb = wgTb + (size_t)s * 16 * 512;
  float sq = 0.f;
  for (int g = tid; g < C_CH * FT / 4; g += 256) {
    float4 a = p0[g], b = p1[g], c = p2[g], w = pw[g];
    float4 v;
    v.x = a.x + b.x + c.x + regv * w.x;
    v.y = a.y + b.y + c.y + regv * w.y;
    v.z = a.z + b.z + c.z + regv * w.z;
    v.w = a.w + b.w + c.w + regv * w.w;
    pg[g] = v;
    sq += v.x * v.x + v.y * v.y + v.z * v.z + v.w * v.w;
    int ch = g >> 2, tq = (g & 3) * 4;
    int k = chperm(ch);
    wb[(tq + 0) * 512 + k] = bf16r(v.x);
    wb[(tq + 1) * 512 + k] = bf16r(v.y);
    wb[(tq + 2) * 512 + k] = bf16r(v.z);
    wb[(tq + 3) * 512 + k] = bf16r(v.w);
  }
  float tot = blk_reduce(sq, rtmp);
  if (tid == 0) nump[s] = tot;
}

// ---------------------------------------------------------------------------
// update: den from S-gathered sg, alpha, weight step, incremental scores,
// next mask/residuals.
// ---------------------------------------------------------------------------
__global__ __launch_bounds__(256) void update_k(
    float* __restrict__ wcur, const float* __restrict__ wg,
    const float* __restrict__ S,
    const float* __restrict__ sw, const float* __restrict__ lm,
    const float* __restrict__ alo, const float* __restrict__ ahi,
    float* __restrict__ scores, float* __restrict__ mask,
    float* __restrict__ rbuf,
    const float* __restrict__ nump, const float* __restrict__ scal)
{
  __shared__ float rtmp[4];
  __shared__ float s_sa;
  int s = blockIdx.x;
  int tid = threadIdx.x;

  float sgl[5];
  float sq = 0.f;
  #pragma unroll
  for (int k = 0; k < 5; ++k) {
    int g = tid + k * 256;
    sgl[k] = 0.f;
    if (g < I_IMG * NPIX) {
      int i = g / NPIX, p = g - i * NPIX;
      int n = i * S_SEQ + s;
      int yo = p / OW, xo = p - yo * OW;
      float sv = s_gather(S + (size_t)n * 16 * SPL, yo, xo);
      sgl[k] = sv;
      int idx = n * NPIX + p;
      float sg = sw[idx] * mask[idx] * sv;
      sq += sg * sg;
    }
  }
  float den = blk_reduce(sq, rtmp);
  if (tid == 0) {
    float num = nump[s];
    float regv = scal[1], step = scal[0];
    float d = fmaxf(den + regv * num, 1e-8f);
    s_sa = step * (num / d);
  }
  __syncthreads();
  float sa = s_sa;

  float4* w4 = (float4*)(wcur + (size_t)s * (C_CH * FT));
  const float4* g4 = (const float4*)(wg + (size_t)s * (C_CH * FT));
  for (int idx = tid; idx < C_CH * FT / 4; idx += 256) {
    float4 w = w4[idx], g = g4[idx];
    w.x -= sa * g.x; w.y -= sa * g.y; w.z -= sa * g.z; w.w -= sa * g.w;
    w4[idx] = w;
  }

  #pragma unroll
  for (int k = 0; k < 5; ++k) {
    int g = tid + k * 256;
    if (g < I_IMG * NPIX) {
      int i = g / NPIX, p = g - i * NPIX;
      int idx = (i * S_SEQ + s) * NPIX + p;
      float sv = scores[idx] - sa * sgl[k];
      scores[idx] = sv;
      float lo = alo[idx], hi = ahi[idx], s_w = sw[idx], l_v = lm[idx];
      float sgn = (sv > 0.f) ? 1.f : ((sv < 0.f) ? -1.f : 0.f);
      float actv = lo * fabsf(sv) + hi * sv;
      float msk = lo * sgn + hi;
      mask[idx] = msk;
      rbuf[idx] = msk * s_w * s_w * (actv - l_v);
    }
  }
}

// ---------------------------------------------------------------------------
extern "C" void kernel_launch(void* const* d_in, const int* in_sizes, int n_in,
                              void* d_out, int out_size, void* d_ws, size_t ws_size,
                              hipStream_t stream)
{
  const float* w_in = (const float*)d_in[0];
  const float* feat = (const float*)d_in[1];
  const float* bb   = (const float*)d_in[2];
  const float* lblw = (const float*)d_in[3];
  const float* mskw = (const float*)d_in[4];
  const float* spw  = (const float*)d_in[5];
  const float* lsl  = (const float*)d_in[6];
  const float* freg = (const float*)d_in[7];

  float* base = (float*)d_ws;
  const int NMAP = I_IMG * S_SEQ * NPIX;   // 69312
  const int NW   = S_SEQ * C_CH * FT;      // 524288
  float* sw     = base;
  float* lm     = sw + NMAP;
  float* alo    = lm + NMAP;
  float* ahi    = alo + NMAP;
  float* mask   = ahi + NMAP;
  float* rbuf   = mask + NMAP;
  float* scores = rbuf + NMAP;
  float* wcur   = scores + NMAP;
  float* wg     = wcur + NW;
  float* wgp    = wg + NW;                 // 3*NW
  float* nump   = wgp + 3 * NW;
  float* scal   = nump + S_SEQ;
  float* Sbuf   = scal + 8;                // 192*16*336
  ushort* wTb   = (ushort*)(Sbuf + (size_t)I_IMG * S_SEQ * 16 * SPL);
  ushort* featT = wTb + (size_t)S_SEQ * 16 * 512;
  ushort* featB = featT + (size_t)I_IMG * S_SEQ * HW * C_CH;

  convert_k<<<dim3(I_IMG * S_SEQ, 16), 256, 0, stream>>>(feat, featT, featB);
  prep_k<<<I_IMG * S_SEQ, 384, 0, stream>>>(bb, lblw, mskw, spw, lsl, freg,
                                            sw, lm, alo, ahi, scal);
  hipMemcpyAsync(wcur, w_in, (size_t)NW * sizeof(float),
                 hipMemcpyDeviceToDevice, stream);

  // initial scores via MFMA GEMM
  wT_k<<<S_SEQ, 256, 0, stream>>>(wcur, wTb);
  mfma_fwd_k<<<dim3(I_IMG * S_SEQ, 6), 256, 0, stream>>>(featT, wTb, Sbuf);
  combine0_k<<<I_IMG * S_SEQ, 384, 0, stream>>>(
      Sbuf, sw, lm, alo, ahi, scores, mask, rbuf);

  for (int it = 0; it < NITER; ++it) {
    mfma_tr_k<<<dim3(6, S_SEQ), 256, 0, stream>>>(featB, rbuf, wgp);
    combine_wg_k<<<S_SEQ, 256, 0, stream>>>(wgp, wcur, scal, wg, wTb, nump);
    mfma_fwd_k<<<dim3(I_IMG * S_SEQ, 6), 256, 0, stream>>>(featT, wTb, Sbuf);
    update_k<<<S_SEQ, 256, 0, stream>>>(
        wcur, wg, Sbuf, sw, lm, alo, ahi, scores, mask, rbuf, nump, scal);
  }
  hipMemcpyAsync(d_out, wcur, (size_t)NW * sizeof(float),
                 hipMemcpyDeviceToDevice, stream);
}

// Round 21
// 385.526 us; speedup vs baseline: 1.2274x; 1.2274x over previous
//
#include <hip/hip_runtime.h>
#include <math.h>

#define I_IMG 3
#define S_SEQ 64
#define C_CH  512
#define H_IN  18
#define W_IN  18
#define HW    324
#define OH 19
#define OW 19
#define NPIX 361
#define FT 16
#define NITER 5
#define RPW 24            // tr rp row stride
#define CVS 32            // uint slots per convert block
#define CVP 162           // pixels per convert block
#define SPL 336           // S plane length (21 tiles x 16)
#define BPL 352           // A-operand padded length (11 x 32)
#define ASTR 360          // A-lds row stride (ushorts)

typedef unsigned int uint;
typedef unsigned short ushort;
typedef float f32x4 __attribute__((ext_vector_type(4)));
typedef short s16x8 __attribute__((ext_vector_type(8)));
typedef uint u32x4 __attribute__((ext_vector_type(4)));

__device__ inline float blk_reduce(float v, float* tmp) {
  #pragma unroll
  for (int o = 32; o > 0; o >>= 1) v += __shfl_down(v, o, 64);
  int lane = threadIdx.x & 63;
  int w = threadIdx.x >> 6;
  if (lane == 0) tmp[w] = v;
  __syncthreads();
  float r = 0.f;
  if (threadIdx.x == 0) {
    int nw = (blockDim.x + 63) >> 6;
    for (int k = 0; k < nw; ++k) r += tmp[k];
  }
  return r;
}

__device__ inline uint pack_bf2(float lo, float hi) {  // RNE f32x2 -> packed bf16x2
  uint ul = __float_as_uint(lo);
  uint uh = __float_as_uint(hi);
  ul = (ul + 0x7fffu + ((ul >> 16) & 1u)) >> 16;
  uh = (uh + 0x7fffu + ((uh >> 16) & 1u)) & 0xffff0000u;
  return ul | uh;
}

__device__ inline ushort bf16r(float f) {  // RNE f32 -> bf16
  uint u = __float_as_uint(f);
  return (ushort)((u + 0x7fffu + ((u >> 16) & 1u)) >> 16);
}

__device__ inline uint cvtpk(float a, float b) {  // HW packed f32x2 -> bf16x2
  uint r;
  asm("v_cvt_pk_bf16_f32 %0, %1, %2" : "=v"(r) : "v"(a), "v"(b));
  return r;
}

// ushort index within featT's packed channel order for natural channel c
__device__ inline int chperm(int c) { return (c < 256) ? 2 * c : 2 * (c - 256) + 1; }

// ---------------------------------------------------------------------------
// convert (R11 exact): feat f32 [n][c][p] -> featT packed-bf16 [n][p][k]
// ---------------------------------------------------------------------------
__global__ __launch_bounds__(256) void convert_k(
    const float* __restrict__ feat, ushort* __restrict__ featT)
{
  __shared__ uint tile[CVP * CVS];   // 20736 B
  int tid = threadIdx.x;
  int n = blockIdx.x;
  int yz = blockIdx.y;
  int k0 = (yz >> 1) * CVS;
  int p0 = (yz & 1) * CVP;
  const float* fbase = feat + (size_t)n * C_CH * HW + p0;

  for (int idx = tid; idx < CVS * 81; idx += 256) {
    int k = idx / 81, q = idx - k * 81;
    int j = k0 + k;
    float2 lo = *(const float2*)(fbase + (size_t)j * HW + 2 * q);
    float2 hi = *(const float2*)(fbase + (size_t)(j + 256) * HW + 2 * q);
    uint b = (uint)(2 * q) * CVS + (uint)(k ^ (q & 31));  // XOR bank swizzle
    tile[b] = pack_bf2(lo.x, hi.x);
    tile[b + CVS] = pack_bf2(lo.y, hi.y);
  }
  __syncthreads();

  uint* dTb = (uint*)featT + ((size_t)n * HW + p0) * (C_CH / 2) + k0;
  for (int idx = tid; idx < CVP * CVS; idx += 256) {
    int px = idx >> 5, k = idx & 31;
    dTb[(size_t)px * (C_CH / 2) + k] = tile[px * CVS + (k ^ ((px >> 1) & 31))];
  }
}

// ---------------------------------------------------------------------------
// prep: distance map -> label_map, sample_weight, a_lo, a_hi; scalars
// ---------------------------------------------------------------------------
__global__ void prep_k(const float* __restrict__ bb,
                       const float* __restrict__ label_w,
                       const float* __restrict__ mask_w,
                       const float* __restrict__ spatial_w,
                       const float* __restrict__ lsl,
                       const float* __restrict__ freg,
                       float* __restrict__ sw, float* __restrict__ lm,
                       float* __restrict__ alo, float* __restrict__ ahi,
                       float* __restrict__ scal)
{
  int n = blockIdx.x;
  int p = threadIdx.x;
  if (n == 0 && p == 0) {
    scal[0] = expf(lsl[0]);
    scal[1] = fmaxf(freg[0] * freg[0], 1e-6f);
  }
  if (p >= NPIX) return;
  float bx = bb[n * 4 + 0], by = bb[n * 4 + 1];
  float bw = bb[n * 4 + 2], bh = bb[n * 4 + 3];
  float crow = (by + bh * 0.5f) * (1.f / 16.f);
  float ccol = (bx + bw * 0.5f) * (1.f / 16.f);
  int y = p / OW, x = p - (p / OW) * OW;
  float d0 = (float)y - crow, d1 = (float)x - ccol;
  float dist = sqrtf(d0 * d0 + d1 * d1);
  float bins[5];
  #pragma unroll
  for (int b = 0; b < 4; ++b) bins[b] = fmaxf(1.f - fabsf(dist - (float)b), 0.f);
  bins[4] = fminf(fmaxf(dist - 3.f, 0.f), 1.f);
  float lmv = 0.f, mm = 0.f, sp = 0.f;
  #pragma unroll
  for (int b = 0; b < 5; ++b) {
    lmv += bins[b] * label_w[b];
    mm  += bins[b] * mask_w[b];
    sp  += bins[b] * spatial_w[b];
  }
  float tm = 1.f / (1.f + expf(-mm));
  int idx = n * NPIX + p;
  lm[idx]  = lmv;
  sw[idx]  = 0.57735026918962584f * sp;
  alo[idx] = 0.5f * (1.f - tm);
  ahi[idx] = 0.5f * (1.f + tm);
}

// ---------------------------------------------------------------------------
// wT_k: w fp32 [s][c][16] -> wTb bf16 [s][t][512] (featT channel order)
// ---------------------------------------------------------------------------
__global__ __launch_bounds__(256) void wT_k(
    const float* __restrict__ w, ushort* __restrict__ wTb)
{
  int s = blockIdx.x;
  const float4* pw = (const float4*)(w + (size_t)s * C_CH * FT);
  ushort* wb = wTb + (size_t)s * 16 * 512;
  for (int g = threadIdx.x; g < C_CH * FT / 4; g += 256) {
    int c = g >> 2, tq = (g & 3) * 4;
    float4 v = pw[g];
    int k = chperm(c);
    wb[(tq + 0) * 512 + k] = bf16r(v.x);
    wb[(tq + 1) * 512 + k] = bf16r(v.y);
    wb[(tq + 2) * 512 + k] = bf16r(v.z);
    wb[(tq + 3) * 512 + k] = bf16r(v.w);
  }
}

// ---------------------------------------------------------------------------
// mfma_fwd (R17-proven): S[n][t][p] = sum_c featT[n][p][c] * wTb[s][t][c]
// ---------------------------------------------------------------------------
__global__ __launch_bounds__(256) void mfma_fwd_k(
    const ushort* __restrict__ featT, const ushort* __restrict__ wTb,
    float* __restrict__ S)
{
  int lane = threadIdx.x & 63;
  int wv = threadIdx.x >> 6;
  int n = blockIdx.x;
  int s = n & 63;
  int mtile = blockIdx.y * 4 + wv;
  if (mtile >= 21) return;
  int mrow = lane & 15;
  int kg = lane >> 4;

  const ushort* wb = wTb + ((size_t)s * 16 + mrow) * 512 + kg * 8;
  s16x8 bfrag[16];
  #pragma unroll
  for (int k0 = 0; k0 < 16; ++k0)
    bfrag[k0] = *(const s16x8*)(wb + k0 * 32);

  int p = mtile * 16 + mrow;
  bool pvalid = p < HW;
  const ushort* fa = featT + ((size_t)n * HW + (pvalid ? p : 0)) * 512 + kg * 8;
  s16x8 zero8 = {0, 0, 0, 0, 0, 0, 0, 0};

  f32x4 acc = {0.f, 0.f, 0.f, 0.f};
  #pragma unroll
  for (int k0 = 0; k0 < 16; ++k0) {
    s16x8 afrag = pvalid ? *(const s16x8*)(fa + k0 * 32) : zero8;
    acc = __builtin_amdgcn_mfma_f32_16x16x32_bf16(afrag, bfrag[k0], acc, 0, 0, 0);
  }

  float* dst = S + ((size_t)n * 16 + mrow) * SPL + mtile * 16 + kg * 4;
  *(float4*)dst = make_float4(acc[0], acc[1], acc[2], acc[3]);
}

// ---------------------------------------------------------------------------
// mfma_tr: wgp[i][s][c][t] = sum_p A[t][p] * feat[(i,s,c)][p]
// B operand loaded from fp32 feat directly, cvt via v_cvt_pk_bf16_f32.
// grid (6,64): blockIdx.x = i*2 + nh; wave wv covers 4 n-tiles.
// ---------------------------------------------------------------------------
__global__ __launch_bounds__(256) void mfma_tr_k(
    const float* __restrict__ feat, const float* __restrict__ r,
    float* __restrict__ wgp)
{
  __shared__ __align__(16) float rp[21 * RPW];
  __shared__ __align__(16) ushort Ald[16 * ASTR];
  int tid = threadIdx.x;
  int i = blockIdx.x >> 1;
  int nh = blockIdx.x & 1;
  int s = blockIdx.y;

  for (int idx = tid; idx < 21 * RPW; idx += 256) rp[idx] = 0.f;
  __syncthreads();
  for (int idx = tid; idx < NPIX; idx += 256) {
    int y = idx / OW, x = idx - y * OW;
    rp[(y + 1) * RPW + (x + 1)] = r[(size_t)(i * S_SEQ + s) * NPIX + idx];
  }
  __syncthreads();

  // A[t][p] = rp[(u+3-dy)*RPW + (v+3-dx)], t=dy*4+dx, p=u*18+v; pad zeros
  for (int idx = tid; idx < 16 * BPL; idx += 256) {
    int t = idx / BPL, pp = idx - t * BPL;
    ushort val = 0;
    if (pp < HW) {
      int u = pp / 18, vv = pp - u * 18;
      int dy = t >> 2, dx = t & 3;
      val = bf16r(rp[(u + 3 - dy) * RPW + (vv + 3 - dx)]);
    }
    Ald[t * ASTR + pp] = val;
  }
  __syncthreads();

  int lane = tid & 63, wv = tid >> 6;
  int nsub = lane & 15, kg = lane >> 4;

  const ushort* arow = Ald + nsub * ASTR + kg * 8;
  s16x8 afr[11];
  #pragma unroll
  for (int ks = 0; ks < 11; ++ks)
    afr[ks] = *(const s16x8*)(arow + ks * 32);

  size_t nsbase = ((size_t)i * S_SEQ + s) * C_CH;
  #pragma unroll
  for (int j = 0; j < 4; ++j) {
    int nt = nh * 16 + wv * 4 + j;
    int c = nt * 16 + nsub;
    const float* fb = feat + (nsbase + c) * (size_t)HW + kg * 8;
    f32x4 acc = {0.f, 0.f, 0.f, 0.f};
    #pragma unroll
    for (int ks = 0; ks < 10; ++ks) {
      float4 x = *(const float4*)(fb + ks * 32);
      float4 y = *(const float4*)(fb + ks * 32 + 4);
      u32x4 t = {cvtpk(x.x, x.y), cvtpk(x.z, x.w),
                 cvtpk(y.x, y.y), cvtpk(y.z, y.w)};
      s16x8 bf = __builtin_bit_cast(s16x8, t);
      acc = __builtin_amdgcn_mfma_f32_16x16x32_bf16(afr[ks], bf, acc, 0, 0, 0);
    }
    {
      // K-tail: pixels 320..323 valid only (kg==0); A is zero past 324
      s16x8 bf = {0, 0, 0, 0, 0, 0, 0, 0};
      if (kg == 0) {
        float4 x = *(const float4*)(fb + 320);
        u32x4 t = {cvtpk(x.x, x.y), cvtpk(x.z, x.w), 0u, 0u};
        bf = __builtin_bit_cast(s16x8, t);
      }
      acc = __builtin_amdgcn_mfma_f32_16x16x32_bf16(afr[10], bf, acc, 0, 0, 0);
    }
    float* dst = wgp + (nsbase + c) * FT + kg * 4;
    *(float4*)dst = make_float4(acc[0], acc[1], acc[2], acc[3]);
  }
}

// ---------------------------------------------------------------------------
// gather scores from S planes
// ---------------------------------------------------------------------------
__device__ inline float s_gather(const float* __restrict__ Sp, int yo, int xo) {
  float sv = 0.f;
  #pragma unroll
  for (int dy = 0; dy < 4; ++dy) {
    int yi = yo + dy - 2;
    if (yi < 0 || yi >= H_IN) continue;
    #pragma unroll
    for (int dx = 0; dx < 4; ++dx) {
      int xi = xo + dx - 2;
      if (xi < 0 || xi >= W_IN) continue;
      sv += Sp[(dy * 4 + dx) * SPL + yi * W_IN + xi];
    }
  }
  return sv;
}

// ---------------------------------------------------------------------------
// combine0 (once): S -> scores + mask + residuals
// ---------------------------------------------------------------------------
__global__ __launch_bounds__(384) void combine0_k(
    const float* __restrict__ S,
    const float* __restrict__ sw, const float* __restrict__ lm,
    const float* __restrict__ alo, const float* __restrict__ ahi,
    float* __restrict__ scores,
    float* __restrict__ mask, float* __restrict__ rbuf)
{
  int n = blockIdx.x;
  int p = threadIdx.x;
  if (p >= NPIX) return;
  int yo = p / OW, xo = p - yo * OW;
  float sv = s_gather(S + (size_t)n * 16 * SPL, yo, xo);
  int idx = n * NPIX + p;
  scores[idx] = sv;
  float lo = alo[idx], hi = ahi[idx], s_w = sw[idx], l_v = lm[idx];
  float sgn = (sv > 0.f) ? 1.f : ((sv < 0.f) ? -1.f : 0.f);
  float actv = lo * fabsf(sv) + hi * sv;
  float msk = lo * sgn + hi;
  mask[idx] = msk;
  rbuf[idx] = msk * s_w * s_w * (actv - l_v);
}

// ---------------------------------------------------------------------------
// combine_wg: wg = sum_i wgp + reg*wcur (fp32) + wgTb bf16 [s][t][512];
// nump[s] = ||wg||^2
// ---------------------------------------------------------------------------
__global__ __launch_bounds__(256) void combine_wg_k(
    const float* __restrict__ wgp, const float* __restrict__ wcur,
    const float* __restrict__ scal,
    float* __restrict__ wg, ushort* __restrict__ wgTb,
    float* __restrict__ nump)
{
  __shared__ float rtmp[4];
  int s = blockIdx.x;
  int tid = threadIdx.x;
  float regv = scal[1];
  size_t base = (size_t)s * C_CH * FT;
  size_t istr = (size_t)S_SEQ * C_CH * FT;
  const float4* p0 = (const float4*)(wgp + base);
  const float4* p1 = (const float4*)(wgp + istr + base);
  const float4* p2 = (const float4*)(wgp + 2 * istr + base);
  const float4* pw = (const float4*)(wcur + base);
  float4* pg = (float4*)(wg + base);
  ushort* wb = wgTb + (size_t)s * 16 * 512;
  float sq = 0.f;
  for (int g = tid; g < C_CH * FT / 4; g += 256) {
    float4 a = p0[g], b = p1[g], c = p2[g], w = pw[g];
    float4 v;
    v.x = a.x + b.x + c.x + regv * w.x;
    v.y = a.y + b.y + c.y + regv * w.y;
    v.z = a.z + b.z + c.z + regv * w.z;
    v.w = a.w + b.w + c.w + regv * w.w;
    pg[g] = v;
    sq += v.x * v.x + v.y * v.y + v.z * v.z + v.w * v.w;
    int ch = g >> 2, tq = (g & 3) * 4;
    int k = chperm(ch);
    wb[(tq + 0) * 512 + k] = bf16r(v.x);
    wb[(tq + 1) * 512 + k] = bf16r(v.y);
    wb[(tq + 2) * 512 + k] = bf16r(v.z);
    wb[(tq + 3) * 512 + k] = bf16r(v.w);
  }
  float tot = blk_reduce(sq, rtmp);
  if (tid == 0) nump[s] = tot;
}

// ---------------------------------------------------------------------------
// update (1024 threads): den from S-gathered sg, alpha, weight step,
// incremental scores, next mask/residuals.
// ---------------------------------------------------------------------------
__global__ __launch_bounds__(1024) void update_k(
    float* __restrict__ wcur, const float* __restrict__ wg,
    const float* __restrict__ S,
    const float* __restrict__ sw, const float* __restrict__ lm,
    const float* __restrict__ alo, const float* __restrict__ ahi,
    float* __restrict__ scores, float* __restrict__ mask,
    float* __restrict__ rbuf,
    const float* __restrict__ nump, const float* __restrict__ scal)
{
  __shared__ float rtmp[16];
  __shared__ float s_sa;
  int s = blockIdx.x;
  int tid = threadIdx.x;

  float sgl[2];
  float sq = 0.f;
  #pragma unroll
  for (int k = 0; k < 2; ++k) {
    int g = tid + k * 1024;
    sgl[k] = 0.f;
    if (g < I_IMG * NPIX) {
      int i = g / NPIX, p = g - i * NPIX;
      int n = i * S_SEQ + s;
      int yo = p / OW, xo = p - yo * OW;
      float sv = s_gather(S + (size_t)n * 16 * SPL, yo, xo);
      sgl[k] = sv;
      int idx = n * NPIX + p;
      float sg = sw[idx] * mask[idx] * sv;
      sq += sg * sg;
    }
  }
  float den = blk_reduce(sq, rtmp);
  if (tid == 0) {
    float num = nump[s];
    float regv = scal[1], step = scal[0];
    float d = fmaxf(den + regv * num, 1e-8f);
    s_sa = step * (num / d);
  }
  __syncthreads();
  float sa = s_sa;

  float4* w4 = (float4*)(wcur + (size_t)s * (C_CH * FT));
  const float4* g4 = (const float4*)(wg + (size_t)s * (C_CH * FT));
  for (int idx = tid; idx < C_CH * FT / 4; idx += 1024) {
    float4 w = w4[idx], g = g4[idx];
    w.x -= sa * g.x; w.y -= sa * g.y; w.z -= sa * g.z; w.w -= sa * g.w;
    w4[idx] = w;
  }

  #pragma unroll
  for (int k = 0; k < 2; ++k) {
    int g = tid + k * 1024;
    if (g < I_IMG * NPIX) {
      int i = g / NPIX, p = g - i * NPIX;
      int idx = (i * S_SEQ + s) * NPIX + p;
      float sv = scores[idx] - sa * sgl[k];
      scores[idx] = sv;
      float lo = alo[idx], hi = ahi[idx], s_w = sw[idx], l_v = lm[idx];
      float sgn = (sv > 0.f) ? 1.f : ((sv < 0.f) ? -1.f : 0.f);
      float actv = lo * fabsf(sv) + hi * sv;
      float msk = lo * sgn + hi;
      mask[idx] = msk;
      rbuf[idx] = msk * s_w * s_w * (actv - l_v);
    }
  }
}

// ---------------------------------------------------------------------------
extern "C" void kernel_launch(void* const* d_in, const int* in_sizes, int n_in,
                              void* d_out, int out_size, void* d_ws, size_t ws_size,
                              hipStream_t stream)
{
  const float* w_in = (const float*)d_in[0];
  const float* feat = (const float*)d_in[1];
  const float* bb   = (const float*)d_in[2];
  const float* lblw = (const float*)d_in[3];
  const float* mskw = (const float*)d_in[4];
  const float* spw  = (const float*)d_in[5];
  const float* lsl  = (const float*)d_in[6];
  const float* freg = (const float*)d_in[7];

  float* base = (float*)d_ws;
  const int NMAP = I_IMG * S_SEQ * NPIX;   // 69312
  const int NW   = S_SEQ * C_CH * FT;      // 524288
  float* sw     = base;
  float* lm     = sw + NMAP;
  float* alo    = lm + NMAP;
  float* ahi    = alo + NMAP;
  float* mask   = ahi + NMAP;
  float* rbuf   = mask + NMAP;
  float* scores = rbuf + NMAP;
  float* wcur   = scores + NMAP;
  float* wg     = wcur + NW;
  float* wgp    = wg + NW;                 // 3*NW
  float* nump   = wgp + 3 * NW;
  float* scal   = nump + S_SEQ;
  float* Sbuf   = scal + 8;                // 192*16*336
  ushort* wTb   = (ushort*)(Sbuf + (size_t)I_IMG * S_SEQ * 16 * SPL);
  ushort* featT = wTb + (size_t)S_SEQ * 16 * 512;

  convert_k<<<dim3(I_IMG * S_SEQ, 16), 256, 0, stream>>>(feat, featT);
  prep_k<<<I_IMG * S_SEQ, 384, 0, stream>>>(bb, lblw, mskw, spw, lsl, freg,
                                            sw, lm, alo, ahi, scal);
  hipMemcpyAsync(wcur, w_in, (size_t)NW * sizeof(float),
                 hipMemcpyDeviceToDevice, stream);

  // initial scores via MFMA GEMM
  wT_k<<<S_SEQ, 256, 0, stream>>>(wcur, wTb);
  mfma_fwd_k<<<dim3(I_IMG * S_SEQ, 6), 256, 0, stream>>>(featT, wTb, Sbuf);
  combine0_k<<<I_IMG * S_SEQ, 384, 0, stream>>>(
      Sbuf, sw, lm, alo, ahi, scores, mask, rbuf);

  for (int it = 0; it < NITER; ++it) {
    mfma_tr_k<<<dim3(6, S_SEQ), 256, 0, stream>>>(feat, rbuf, wgp);
    combine_wg_k<<<S_SEQ, 256, 0, stream>>>(wgp, wcur, scal, wg, wTb, nump);
    mfma_fwd_k<<<dim3(I_IMG * S_SEQ, 6), 256, 0, stream>>>(featT, wTb, Sbuf);
    update_k<<<S_SEQ, 1024, 0, stream>>>(
        wcur, wg, Sbuf, sw, lm, alo, ahi, scores, mask, rbuf, nump, scal);
  }
  hipMemcpyAsync(d_out, wcur, (size_t)NW * sizeof(float),
                 hipMemcpyDeviceToDevice, stream);
}

// Round 22
// 379.836 us; speedup vs baseline: 1.2458x; 1.0150x over previous
//
#include <hip/hip_runtime.h>
#include <math.h>

#define I_IMG 3
#define S_SEQ 64
#define C_CH  512
#define H_IN  18
#define W_IN  18
#define HW    324
#define OH 19
#define OW 19
#define NPIX 361
#define FT 16
#define NITER 5
#define RPW 24            // tr rp row stride
#define CVS 32            // uint slots per convert block
#define CVPX 108          // pixels per convert block (324 = 3*108)
#define CVQ 27            // float4 quads per block
#define SPL 336           // S plane length (21 tiles x 16)
#define BPL 352           // A-operand padded length (11 x 32)
#define ASTR 360          // A-lds row stride (ushorts)

typedef unsigned int uint;
typedef unsigned short ushort;
typedef float f32x4 __attribute__((ext_vector_type(4)));
typedef short s16x8 __attribute__((ext_vector_type(8)));
typedef uint u32x4 __attribute__((ext_vector_type(4)));

__device__ inline float blk_reduce(float v, float* tmp) {
  #pragma unroll
  for (int o = 32; o > 0; o >>= 1) v += __shfl_down(v, o, 64);
  int lane = threadIdx.x & 63;
  int w = threadIdx.x >> 6;
  if (lane == 0) tmp[w] = v;
  __syncthreads();
  float r = 0.f;
  if (threadIdx.x == 0) {
    int nw = (blockDim.x + 63) >> 6;
    for (int k = 0; k < nw; ++k) r += tmp[k];
  }
  return r;
}

__device__ inline uint pack_bf2(float lo, float hi) {  // RNE f32x2 -> packed bf16x2
  uint ul = __float_as_uint(lo);
  uint uh = __float_as_uint(hi);
  ul = (ul + 0x7fffu + ((ul >> 16) & 1u)) >> 16;
  uh = (uh + 0x7fffu + ((uh >> 16) & 1u)) & 0xffff0000u;
  return ul | uh;
}

__device__ inline ushort bf16r(float f) {  // RNE f32 -> bf16
  uint u = __float_as_uint(f);
  return (ushort)((u + 0x7fffu + ((u >> 16) & 1u)) >> 16);
}

__device__ inline uint cvtpk(float a, float b) {  // HW packed f32x2 -> bf16x2
  uint r;
  asm("v_cvt_pk_bf16_f32 %0, %1, %2" : "=v"(r) : "v"(a), "v"(b));
  return r;
}

// ushort index within featT's packed channel order for natural channel c
__device__ inline int chperm(int c) { return (c < 256) ? 2 * c : 2 * (c - 256) + 1; }

// ---------------------------------------------------------------------------
// convert v2: feat f32 [n][c][p] -> featT packed-bf16 [n][p][k]
// grid (192, 24): block = (n, 8 k-tiles x 3 p-tiles of 108 px).
// 13.8KB LDS -> 8 blocks/CU (100% wave occupancy); float4 reads.
// ---------------------------------------------------------------------------
__global__ __launch_bounds__(256) void convert_k(
    const float* __restrict__ feat, ushort* __restrict__ featT)
{
  __shared__ uint tile[CVPX * CVS];   // 13824 B
  int tid = threadIdx.x;
  int n = blockIdx.x;
  int yz = blockIdx.y;
  int k0 = (yz >> 2) * CVS;           // yz/4? no: 8 k-tiles x 3 p-tiles
  // decode: kt in [0,8), pt in [0,3)
  int kt = yz / 3, pt = yz - kt * 3;
  k0 = kt * CVS;
  int p0 = pt * CVPX;
  const float* fbase = feat + (size_t)n * C_CH * HW + p0;

  // stage: idx -> (k = idx/27, q = idx%27); lanes walk q (coalesced float4)
  for (int idx = tid; idx < CVS * CVQ; idx += 256) {
    int k = idx / CVQ, q = idx - k * CVQ;
    int j = k0 + k;
    const float* src = fbase + (size_t)j * HW + 4 * q;
    float4 lo = *(const float4*)src;
    float4 hi = *(const float4*)(src + 256 * HW);
    uint b = (uint)(4 * q) * CVS + (uint)(k ^ (q & 31));  // XOR bank swizzle
    tile[b] = pack_bf2(lo.x, hi.x);
    tile[b + CVS] = pack_bf2(lo.y, hi.y);
    tile[b + 2 * CVS] = pack_bf2(lo.z, hi.z);
    tile[b + 3 * CVS] = pack_bf2(lo.w, hi.w);
  }
  __syncthreads();

  // output: idx -> (px = idx>>5, k = idx&31); 32 lanes cover one 128B line
  uint* dTb = (uint*)featT + ((size_t)n * HW + p0) * (C_CH / 2) + k0;
  for (int idx = tid; idx < CVPX * CVS; idx += 256) {
    int px = idx >> 5, k = idx & 31;
    dTb[(size_t)px * (C_CH / 2) + k] = tile[px * CVS + (k ^ ((px >> 2) & 31))];
  }
}

// ---------------------------------------------------------------------------
// prep: distance map -> label_map, sample_weight, a_lo, a_hi; scalars
// ---------------------------------------------------------------------------
__global__ void prep_k(const float* __restrict__ bb,
                       const float* __restrict__ label_w,
                       const float* __restrict__ mask_w,
                       const float* __restrict__ spatial_w,
                       const float* __restrict__ lsl,
                       const float* __restrict__ freg,
                       float* __restrict__ sw, float* __restrict__ lm,
                       float* __restrict__ alo, float* __restrict__ ahi,
                       float* __restrict__ scal)
{
  int n = blockIdx.x;
  int p = threadIdx.x;
  if (n == 0 && p == 0) {
    scal[0] = expf(lsl[0]);
    scal[1] = fmaxf(freg[0] * freg[0], 1e-6f);
  }
  if (p >= NPIX) return;
  float bx = bb[n * 4 + 0], by = bb[n * 4 + 1];
  float bw = bb[n * 4 + 2], bh = bb[n * 4 + 3];
  float crow = (by + bh * 0.5f) * (1.f / 16.f);
  float ccol = (bx + bw * 0.5f) * (1.f / 16.f);
  int y = p / OW, x = p - (p / OW) * OW;
  float d0 = (float)y - crow, d1 = (float)x - ccol;
  float dist = sqrtf(d0 * d0 + d1 * d1);
  float bins[5];
  #pragma unroll
  for (int b = 0; b < 4; ++b) bins[b] = fmaxf(1.f - fabsf(dist - (float)b), 0.f);
  bins[4] = fminf(fmaxf(dist - 3.f, 0.f), 1.f);
  float lmv = 0.f, mm = 0.f, sp = 0.f;
  #pragma unroll
  for (int b = 0; b < 5; ++b) {
    lmv += bins[b] * label_w[b];
    mm  += bins[b] * mask_w[b];
    sp  += bins[b] * spatial_w[b];
  }
  float tm = 1.f / (1.f + expf(-mm));
  int idx = n * NPIX + p;
  lm[idx]  = lmv;
  sw[idx]  = 0.57735026918962584f * sp;
  alo[idx] = 0.5f * (1.f - tm);
  ahi[idx] = 0.5f * (1.f + tm);
}

// ---------------------------------------------------------------------------
// wT_k: w fp32 [s][c][16] -> wTb bf16 [s][t][512] (featT channel order)
// ---------------------------------------------------------------------------
__global__ __launch_bounds__(256) void wT_k(
    const float* __restrict__ w, ushort* __restrict__ wTb)
{
  int s = blockIdx.x;
  const float4* pw = (const float4*)(w + (size_t)s * C_CH * FT);
  ushort* wb = wTb + (size_t)s * 16 * 512;
  for (int g = threadIdx.x; g < C_CH * FT / 4; g += 256) {
    int c = g >> 2, tq = (g & 3) * 4;
    float4 v = pw[g];
    int k = chperm(c);
    wb[(tq + 0) * 512 + k] = bf16r(v.x);
    wb[(tq + 1) * 512 + k] = bf16r(v.y);
    wb[(tq + 2) * 512 + k] = bf16r(v.z);
    wb[(tq + 3) * 512 + k] = bf16r(v.w);
  }
}

// ---------------------------------------------------------------------------
// mfma_fwd (R17-proven): S[n][t][p] = sum_c featT[n][p][c] * wTb[s][t][c]
// ---------------------------------------------------------------------------
__global__ __launch_bounds__(256) void mfma_fwd_k(
    const ushort* __restrict__ featT, const ushort* __restrict__ wTb,
    float* __restrict__ S)
{
  int lane = threadIdx.x & 63;
  int wv = threadIdx.x >> 6;
  int n = blockIdx.x;
  int s = n & 63;
  int mtile = blockIdx.y * 4 + wv;
  if (mtile >= 21) return;
  int mrow = lane & 15;
  int kg = lane >> 4;

  const ushort* wb = wTb + ((size_t)s * 16 + mrow) * 512 + kg * 8;
  s16x8 bfrag[16];
  #pragma unroll
  for (int k0 = 0; k0 < 16; ++k0)
    bfrag[k0] = *(const s16x8*)(wb + k0 * 32);

  int p = mtile * 16 + mrow;
  bool pvalid = p < HW;
  const ushort* fa = featT + ((size_t)n * HW + (pvalid ? p : 0)) * 512 + kg * 8;
  s16x8 zero8 = {0, 0, 0, 0, 0, 0, 0, 0};

  f32x4 acc = {0.f, 0.f, 0.f, 0.f};
  #pragma unroll
  for (int k0 = 0; k0 < 16; ++k0) {
    s16x8 afrag = pvalid ? *(const s16x8*)(fa + k0 * 32) : zero8;
    acc = __builtin_amdgcn_mfma_f32_16x16x32_bf16(afrag, bfrag[k0], acc, 0, 0, 0);
  }

  float* dst = S + ((size_t)n * 16 + mrow) * SPL + mtile * 16 + kg * 4;
  *(float4*)dst = make_float4(acc[0], acc[1], acc[2], acc[3]);
}

// ---------------------------------------------------------------------------
// mfma_tr (R21-proven): wgp[i][s][c][t] = sum_p A[t][p] * feat[(i,s,c)][p]
// B from fp32 feat with v_cvt_pk_bf16_f32. grid (6,64).
// ---------------------------------------------------------------------------
__global__ __launch_bounds__(256) void mfma_tr_k(
    const float* __restrict__ feat, const float* __restrict__ r,
    float* __restrict__ wgp)
{
  __shared__ __align__(16) float rp[21 * RPW];
  __shared__ __align__(16) ushort Ald[16 * ASTR];
  int tid = threadIdx.x;
  int i = blockIdx.x >> 1;
  int nh = blockIdx.x & 1;
  int s = blockIdx.y;

  for (int idx = tid; idx < 21 * RPW; idx += 256) rp[idx] = 0.f;
  __syncthreads();
  for (int idx = tid; idx < NPIX; idx += 256) {
    int y = idx / OW, x = idx - y * OW;
    rp[(y + 1) * RPW + (x + 1)] = r[(size_t)(i * S_SEQ + s) * NPIX + idx];
  }
  __syncthreads();

  for (int idx = tid; idx < 16 * BPL; idx += 256) {
    int t = idx / BPL, pp = idx - t * BPL;
    ushort val = 0;
    if (pp < HW) {
      int u = pp / 18, vv = pp - u * 18;
      int dy = t >> 2, dx = t & 3;
      val = bf16r(rp[(u + 3 - dy) * RPW + (vv + 3 - dx)]);
    }
    Ald[t * ASTR + pp] = val;
  }
  __syncthreads();

  int lane = tid & 63, wv = tid >> 6;
  int nsub = lane & 15, kg = lane >> 4;

  const ushort* arow = Ald + nsub * ASTR + kg * 8;
  s16x8 afr[11];
  #pragma unroll
  for (int ks = 0; ks < 11; ++ks)
    afr[ks] = *(const s16x8*)(arow + ks * 32);

  size_t nsbase = ((size_t)i * S_SEQ + s) * C_CH;
  #pragma unroll
  for (int j = 0; j < 4; ++j) {
    int nt = nh * 16 + wv * 4 + j;
    int c = nt * 16 + nsub;
    const float* fb = feat + (nsbase + c) * (size_t)HW + kg * 8;
    f32x4 acc = {0.f, 0.f, 0.f, 0.f};
    #pragma unroll
    for (int ks = 0; ks < 10; ++ks) {
      float4 x = *(const float4*)(fb + ks * 32);
      float4 y = *(const float4*)(fb + ks * 32 + 4);
      u32x4 t = {cvtpk(x.x, x.y), cvtpk(x.z, x.w),
                 cvtpk(y.x, y.y), cvtpk(y.z, y.w)};
      s16x8 bf = __builtin_bit_cast(s16x8, t);
      acc = __builtin_amdgcn_mfma_f32_16x16x32_bf16(afr[ks], bf, acc, 0, 0, 0);
    }
    {
      s16x8 bf = {0, 0, 0, 0, 0, 0, 0, 0};
      if (kg == 0) {
        float4 x = *(const float4*)(fb + 320);
        u32x4 t = {cvtpk(x.x, x.y), cvtpk(x.z, x.w), 0u, 0u};
        bf = __builtin_bit_cast(s16x8, t);
      }
      acc = __builtin_amdgcn_mfma_f32_16x16x32_bf16(afr[10], bf, acc, 0, 0, 0);
    }
    float* dst = wgp + (nsbase + c) * FT + kg * 4;
    *(float4*)dst = make_float4(acc[0], acc[1], acc[2], acc[3]);
  }
}

// ---------------------------------------------------------------------------
// gather scores from S planes
// ---------------------------------------------------------------------------
__device__ inline float s_gather(const float* __restrict__ Sp, int yo, int xo) {
  float sv = 0.f;
  #pragma unroll
  for (int dy = 0; dy < 4; ++dy) {
    int yi = yo + dy - 2;
    if (yi < 0 || yi >= H_IN) continue;
    #pragma unroll
    for (int dx = 0; dx < 4; ++dx) {
      int xi = xo + dx - 2;
      if (xi < 0 || xi >= W_IN) continue;
      sv += Sp[(dy * 4 + dx) * SPL + yi * W_IN + xi];
    }
  }
  return sv;
}

// ---------------------------------------------------------------------------
// combine0 (once): S -> scores + mask + residuals
// ---------------------------------------------------------------------------
__global__ __launch_bounds__(384) void combine0_k(
    const float* __restrict__ S,
    const float* __restrict__ sw, const float* __restrict__ lm,
    const float* __restrict__ alo, const float* __restrict__ ahi,
    float* __restrict__ scores,
    float* __restrict__ mask, float* __restrict__ rbuf)
{
  int n = blockIdx.x;
  int p = threadIdx.x;
  if (p >= NPIX) return;
  int yo = p / OW, xo = p - yo * OW;
  float sv = s_gather(S + (size_t)n * 16 * SPL, yo, xo);
  int idx = n * NPIX + p;
  scores[idx] = sv;
  float lo = alo[idx], hi = ahi[idx], s_w = sw[idx], l_v = lm[idx];
  float sgn = (sv > 0.f) ? 1.f : ((sv < 0.f) ? -1.f : 0.f);
  float actv = lo * fabsf(sv) + hi * sv;
  float msk = lo * sgn + hi;
  mask[idx] = msk;
  rbuf[idx] = msk * s_w * s_w * (actv - l_v);
}

// ---------------------------------------------------------------------------
// combine_wg (1024 threads): wg = sum_i wgp + reg*wcur; wgTb bf16; nump
// ---------------------------------------------------------------------------
__global__ __launch_bounds__(1024) void combine_wg_k(
    const float* __restrict__ wgp, const float* __restrict__ wcur,
    const float* __restrict__ scal,
    float* __restrict__ wg, ushort* __restrict__ wgTb,
    float* __restrict__ nump)
{
  __shared__ float rtmp[16];
  int s = blockIdx.x;
  int tid = threadIdx.x;
  float regv = scal[1];
  size_t base = (size_t)s * C_CH * FT;
  size_t istr = (size_t)S_SEQ * C_CH * FT;
  const float4* p0 = (const float4*)(wgp + base);
  const float4* p1 = (const float4*)(wgp + istr + base);
  const float4* p2 = (const float4*)(wgp + 2 * istr + base);
  const float4* pw = (const float4*)(wcur + base);
  float4* pg = (float4*)(wg + base);
  ushort* wb = wgTb + (size_t)s * 16 * 512;
  float sq = 0.f;
  for (int g = tid; g < C_CH * FT / 4; g += 1024) {
    float4 a = p0[g], b = p1[g], c = p2[g], w = pw[g];
    float4 v;
    v.x = a.x + b.x + c.x + regv * w.x;
    v.y = a.y + b.y + c.y + regv * w.y;
    v.z = a.z + b.z + c.z + regv * w.z;
    v.w = a.w + b.w + c.w + regv * w.w;
    pg[g] = v;
    sq += v.x * v.x + v.y * v.y + v.z * v.z + v.w * v.w;
    int ch = g >> 2, tq = (g & 3) * 4;
    int k = chperm(ch);
    wb[(tq + 0) * 512 + k] = bf16r(v.x);
    wb[(tq + 1) * 512 + k] = bf16r(v.y);
    wb[(tq + 2) * 512 + k] = bf16r(v.z);
    wb[(tq + 3) * 512 + k] = bf16r(v.w);
  }
  float tot = blk_reduce(sq, rtmp);
  if (tid == 0) nump[s] = tot;
}

// ---------------------------------------------------------------------------
// update (1024 threads): den from S-gathered sg, alpha, weight step,
// incremental scores, next mask/residuals.
// ---------------------------------------------------------------------------
__global__ __launch_bounds__(1024) void update_k(
    float* __restrict__ wcur, const float* __restrict__ wg,
    const float* __restrict__ S,
    const float* __restrict__ sw, const float* __restrict__ lm,
    const float* __restrict__ alo, const float* __restrict__ ahi,
    float* __restrict__ scores, float* __restrict__ mask,
    float* __restrict__ rbuf,
    const float* __restrict__ nump, const float* __restrict__ scal)
{
  __shared__ float rtmp[16];
  __shared__ float s_sa;
  int s = blockIdx.x;
  int tid = threadIdx.x;

  float sgl[2];
  float sq = 0.f;
  #pragma unroll
  for (int k = 0; k < 2; ++k) {
    int g = tid + k * 1024;
    sgl[k] = 0.f;
    if (g < I_IMG * NPIX) {
      int i = g / NPIX, p = g - i * NPIX;
      int n = i * S_SEQ + s;
      int yo = p / OW, xo = p - yo * OW;
      float sv = s_gather(S + (size_t)n * 16 * SPL, yo, xo);
      sgl[k] = sv;
      int idx = n * NPIX + p;
      float sg = sw[idx] * mask[idx] * sv;
      sq += sg * sg;
    }
  }
  float den = blk_reduce(sq, rtmp);
  if (tid == 0) {
    float num = nump[s];
    float regv = scal[1], step = scal[0];
    float d = fmaxf(den + regv * num, 1e-8f);
    s_sa = step * (num / d);
  }
  __syncthreads();
  float sa = s_sa;

  float4* w4 = (float4*)(wcur + (size_t)s * (C_CH * FT));
  const float4* g4 = (const float4*)(wg + (size_t)s * (C_CH * FT));
  for (int idx = tid; idx < C_CH * FT / 4; idx += 1024) {
    float4 w = w4[idx], g = g4[idx];
    w.x -= sa * g.x; w.y -= sa * g.y; w.z -= sa * g.z; w.w -= sa * g.w;
    w4[idx] = w;
  }

  #pragma unroll
  for (int k = 0; k < 2; ++k) {
    int g = tid + k * 1024;
    if (g < I_IMG * NPIX) {
      int i = g / NPIX, p = g - i * NPIX;
      int idx = (i * S_SEQ + s) * NPIX + p;
      float sv = scores[idx] - sa * sgl[k];
      scores[idx] = sv;
      float lo = alo[idx], hi = ahi[idx], s_w = sw[idx], l_v = lm[idx];
      float sgn = (sv > 0.f) ? 1.f : ((sv < 0.f) ? -1.f : 0.f);
      float actv = lo * fabsf(sv) + hi * sv;
      float msk = lo * sgn + hi;
      mask[idx] = msk;
      rbuf[idx] = msk * s_w * s_w * (actv - l_v);
    }
  }
}

// ---------------------------------------------------------------------------
extern "C" void kernel_launch(void* const* d_in, const int* in_sizes, int n_in,
                              void* d_out, int out_size, void* d_ws, size_t ws_size,
                              hipStream_t stream)
{
  const float* w_in = (const float*)d_in[0];
  const float* feat = (const float*)d_in[1];
  const float* bb   = (const float*)d_in[2];
  const float* lblw = (const float*)d_in[3];
  const float* mskw = (const float*)d_in[4];
  const float* spw  = (const float*)d_in[5];
  const float* lsl  = (const float*)d_in[6];
  const float* freg = (const float*)d_in[7];

  float* base = (float*)d_ws;
  const int NMAP = I_IMG * S_SEQ * NPIX;   // 69312
  const int NW   = S_SEQ * C_CH * FT;      // 524288
  float* sw     = base;
  float* lm     = sw + NMAP;
  float* alo    = lm + NMAP;
  float* ahi    = alo + NMAP;
  float* mask   = ahi + NMAP;
  float* rbuf   = mask + NMAP;
  float* scores = rbuf + NMAP;
  float* wcur   = scores + NMAP;
  float* wg     = wcur + NW;
  float* wgp    = wg + NW;                 // 3*NW
  float* nump   = wgp + 3 * NW;
  float* scal   = nump + S_SEQ;
  float* Sbuf   = scal + 8;                // 192*16*336
  ushort* wTb   = (ushort*)(Sbuf + (size_t)I_IMG * S_SEQ * 16 * SPL);
  ushort* featT = wTb + (size_t)S_SEQ * 16 * 512;

  convert_k<<<dim3(I_IMG * S_SEQ, 24), 256, 0, stream>>>(feat, featT);
  prep_k<<<I_IMG * S_SEQ, 384, 0, stream>>>(bb, lblw, mskw, spw, lsl, freg,
                                            sw, lm, alo, ahi, scal);
  hipMemcpyAsync(wcur, w_in, (size_t)NW * sizeof(float),
                 hipMemcpyDeviceToDevice, stream);

  // initial scores via MFMA GEMM
  wT_k<<<S_SEQ, 256, 0, stream>>>(wcur, wTb);
  mfma_fwd_k<<<dim3(I_IMG * S_SEQ, 6), 256, 0, stream>>>(featT, wTb, Sbuf);
  combine0_k<<<I_IMG * S_SEQ, 384, 0, stream>>>(
      Sbuf, sw, lm, alo, ahi, scores, mask, rbuf);

  for (int it = 0; it < NITER; ++it) {
    mfma_tr_k<<<dim3(6, S_SEQ), 256, 0, stream>>>(feat, rbuf, wgp);
    combine_wg_k<<<S_SEQ, 1024, 0, stream>>>(wgp, wcur, scal, wg, wTb, nump);
    mfma_fwd_k<<<dim3(I_IMG * S_SEQ, 6), 256, 0, stream>>>(featT, wTb, Sbuf);
    update_k<<<S_SEQ, 1024, 0, stream>>>(
        wcur, wg, Sbuf, sw, lm, alo, ahi, scores, mask, rbuf, nump, scal);
  }
  hipMemcpyAsync(d_out, wcur, (size_t)NW * sizeof(float),
                 hipMemcpyDeviceToDevice, stream);
}

// Round 23
// 373.436 us; speedup vs baseline: 1.2672x; 1.0171x over previous
//
#include <hip/hip_runtime.h>
#include <math.h>

#define I_IMG 3
#define S_SEQ 64
#define C_CH  512
#define H_IN  18
#define W_IN  18
#define HW    324
#define OH 19
#define OW 19
#define NPIX 361
#define FT 16
#define NITER 5
#define RPW 24            // tr rp row stride
#define CVS 32            // uint slots per convert block
#define CVPX 108          // pixels per convert block (324 = 3*108)
#define CVQ 27            // float4 quads per block
#define SPL 336           // S plane length (21 tiles x 16)
#define BPL 352           // A-operand padded length (11 x 32)
#define ASTR 360          // A-lds row stride (ushorts)

typedef unsigned int uint;
typedef unsigned short ushort;
typedef float f32x4 __attribute__((ext_vector_type(4)));
typedef short s16x8 __attribute__((ext_vector_type(8)));
typedef uint u32x4 __attribute__((ext_vector_type(4)));

__device__ inline float blk_reduce(float v, float* tmp) {
  #pragma unroll
  for (int o = 32; o > 0; o >>= 1) v += __shfl_down(v, o, 64);
  int lane = threadIdx.x & 63;
  int w = threadIdx.x >> 6;
  if (lane == 0) tmp[w] = v;
  __syncthreads();
  float r = 0.f;
  if (threadIdx.x == 0) {
    int nw = (blockDim.x + 63) >> 6;
    for (int k = 0; k < nw; ++k) r += tmp[k];
  }
  return r;
}

__device__ inline uint pack_bf2(float lo, float hi) {  // RNE f32x2 -> packed bf16x2
  uint ul = __float_as_uint(lo);
  uint uh = __float_as_uint(hi);
  ul = (ul + 0x7fffu + ((ul >> 16) & 1u)) >> 16;
  uh = (uh + 0x7fffu + ((uh >> 16) & 1u)) & 0xffff0000u;
  return ul | uh;
}

__device__ inline ushort bf16r(float f) {  // RNE f32 -> bf16
  uint u = __float_as_uint(f);
  return (ushort)((u + 0x7fffu + ((u >> 16) & 1u)) >> 16);
}

__device__ inline uint cvtpk(float a, float b) {  // HW packed f32x2 -> bf16x2
  uint r;
  asm("v_cvt_pk_bf16_f32 %0, %1, %2" : "=v"(r) : "v"(a), "v"(b));
  return r;
}

// ---------------------------------------------------------------------------
// convert v3: feat f32 [n][c][p] -> featT bf16 [n][p][c] (natural channel
// order; uint slot k packs adjacent channels 2k,2k+1 -> contiguous reads).
// grid (192, 24): block = (n, kt in 8, pt in 3).
// ---------------------------------------------------------------------------
__global__ __launch_bounds__(256) void convert_k(
    const float* __restrict__ feat, ushort* __restrict__ featT)
{
  __shared__ uint tile[CVPX * CVS];   // 13824 B
  int tid = threadIdx.x;
  int n = blockIdx.x;
  int yz = blockIdx.y;
  int kt = yz / 3, pt = yz - kt * 3;
  int k0 = kt * CVS;
  int p0 = pt * CVPX;
  const float* fbase = feat + (size_t)n * C_CH * HW + p0;

  // stage: idx -> (k, q); slot k0+k = channels 2(k0+k), 2(k0+k)+1
  for (int idx = tid; idx < CVS * CVQ; idx += 256) {
    int k = idx / CVQ, q = idx - k * CVQ;
    int j = k0 + k;
    const float* src = fbase + (size_t)(2 * j) * HW + 4 * q;
    float4 lo = *(const float4*)src;
    float4 hi = *(const float4*)(src + HW);
    uint b = (uint)(4 * q) * CVS + (uint)(k ^ (q & 31));  // XOR bank swizzle
    tile[b] = pack_bf2(lo.x, hi.x);
    tile[b + CVS] = pack_bf2(lo.y, hi.y);
    tile[b + 2 * CVS] = pack_bf2(lo.z, hi.z);
    tile[b + 3 * CVS] = pack_bf2(lo.w, hi.w);
  }
  __syncthreads();

  // output: 32 lanes cover one 128B line per pixel
  uint* dTb = (uint*)featT + ((size_t)n * HW + p0) * (C_CH / 2) + k0;
  for (int idx = tid; idx < CVPX * CVS; idx += 256) {
    int px = idx >> 5, k = idx & 31;
    dTb[(size_t)px * (C_CH / 2) + k] = tile[px * CVS + (k ^ ((px >> 2) & 31))];
  }
}

// ---------------------------------------------------------------------------
// prep: distance map -> label_map, sample_weight, a_lo, a_hi; scalars
// ---------------------------------------------------------------------------
__global__ void prep_k(const float* __restrict__ bb,
                       const float* __restrict__ label_w,
                       const float* __restrict__ mask_w,
                       const float* __restrict__ spatial_w,
                       const float* __restrict__ lsl,
                       const float* __restrict__ freg,
                       float* __restrict__ sw, float* __restrict__ lm,
                       float* __restrict__ alo, float* __restrict__ ahi,
                       float* __restrict__ scal)
{
  int n = blockIdx.x;
  int p = threadIdx.x;
  if (n == 0 && p == 0) {
    scal[0] = expf(lsl[0]);
    scal[1] = fmaxf(freg[0] * freg[0], 1e-6f);
  }
  if (p >= NPIX) return;
  float bx = bb[n * 4 + 0], by = bb[n * 4 + 1];
  float bw = bb[n * 4 + 2], bh = bb[n * 4 + 3];
  float crow = (by + bh * 0.5f) * (1.f / 16.f);
  float ccol = (bx + bw * 0.5f) * (1.f / 16.f);
  int y = p / OW, x = p - (p / OW) * OW;
  float d0 = (float)y - crow, d1 = (float)x - ccol;
  float dist = sqrtf(d0 * d0 + d1 * d1);
  float bins[5];
  #pragma unroll
  for (int b = 0; b < 4; ++b) bins[b] = fmaxf(1.f - fabsf(dist - (float)b), 0.f);
  bins[4] = fminf(fmaxf(dist - 3.f, 0.f), 1.f);
  float lmv = 0.f, mm = 0.f, sp = 0.f;
  #pragma unroll
  for (int b = 0; b < 5; ++b) {
    lmv += bins[b] * label_w[b];
    mm  += bins[b] * mask_w[b];
    sp  += bins[b] * spatial_w[b];
  }
  float tm = 1.f / (1.f + expf(-mm));
  int idx = n * NPIX + p;
  lm[idx]  = lmv;
  sw[idx]  = 0.57735026918962584f * sp;
  alo[idx] = 0.5f * (1.f - tm);
  ahi[idx] = 0.5f * (1.f + tm);
}

// ---------------------------------------------------------------------------
// wT_k: w fp32 [s][c][16] -> wTb bf16 [s][t][512] (natural channel order)
// ---------------------------------------------------------------------------
__global__ __launch_bounds__(256) void wT_k(
    const float* __restrict__ w, ushort* __restrict__ wTb)
{
  int s = blockIdx.x;
  const float4* pw = (const float4*)(w + (size_t)s * C_CH * FT);
  ushort* wb = wTb + (size_t)s * 16 * 512;
  for (int g = threadIdx.x; g < C_CH * FT / 4; g += 256) {
    int c = g >> 2, tq = (g & 3) * 4;
    float4 v = pw[g];
    wb[(tq + 0) * 512 + c] = bf16r(v.x);
    wb[(tq + 1) * 512 + c] = bf16r(v.y);
    wb[(tq + 2) * 512 + c] = bf16r(v.z);
    wb[(tq + 3) * 512 + c] = bf16r(v.w);
  }
}

// ---------------------------------------------------------------------------
// mfma_fwd (R17-proven): S[n][t][p] = sum_c featT[n][p][c] * wTb[s][t][c]
// ---------------------------------------------------------------------------
__global__ __launch_bounds__(256) void mfma_fwd_k(
    const ushort* __restrict__ featT, const ushort* __restrict__ wTb,
    float* __restrict__ S)
{
  int lane = threadIdx.x & 63;
  int wv = threadIdx.x >> 6;
  int n = blockIdx.x;
  int s = n & 63;
  int mtile = blockIdx.y * 4 + wv;
  if (mtile >= 21) return;
  int mrow = lane & 15;
  int kg = lane >> 4;

  const ushort* wb = wTb + ((size_t)s * 16 + mrow) * 512 + kg * 8;
  s16x8 bfrag[16];
  #pragma unroll
  for (int k0 = 0; k0 < 16; ++k0)
    bfrag[k0] = *(const s16x8*)(wb + k0 * 32);

  int p = mtile * 16 + mrow;
  bool pvalid = p < HW;
  const ushort* fa = featT + ((size_t)n * HW + (pvalid ? p : 0)) * 512 + kg * 8;
  s16x8 zero8 = {0, 0, 0, 0, 0, 0, 0, 0};

  f32x4 acc = {0.f, 0.f, 0.f, 0.f};
  #pragma unroll
  for (int k0 = 0; k0 < 16; ++k0) {
    s16x8 afrag = pvalid ? *(const s16x8*)(fa + k0 * 32) : zero8;
    acc = __builtin_amdgcn_mfma_f32_16x16x32_bf16(afrag, bfrag[k0], acc, 0, 0, 0);
  }

  float* dst = S + ((size_t)n * 16 + mrow) * SPL + mtile * 16 + kg * 4;
  *(float4*)dst = make_float4(acc[0], acc[1], acc[2], acc[3]);
}

// ---------------------------------------------------------------------------
// mfma_tr v2 (fused combine_wg): accumulates over the 3 images in-register,
// then epilogue adds reg*wcur, writes wg fp32 + wTb bf16, reduces ||wg||^2.
// grid (8, 64): block = (64-channel tile cb, s); wave = one 16-ch n-tile.
// ---------------------------------------------------------------------------
__global__ __launch_bounds__(256) void mfma_tr_k(
    const float* __restrict__ feat, const float* __restrict__ r,
    const float* __restrict__ wcur, const float* __restrict__ scal,
    float* __restrict__ wg, ushort* __restrict__ wTb,
    float* __restrict__ numpp)
{
  __shared__ __align__(16) float rp[21 * RPW];
  __shared__ __align__(16) ushort Ald[16 * ASTR];
  __shared__ float rtmp[4];
  int tid = threadIdx.x;
  int cb = blockIdx.x;        // 0..7
  int s = blockIdx.y;
  int lane = tid & 63, wv = tid >> 6;
  int nsub = lane & 15, kg = lane >> 4;
  int c = (cb * 4 + wv) * 16 + nsub;
  float regv = scal[1];

  for (int idx = tid; idx < 21 * RPW; idx += 256) rp[idx] = 0.f;

  f32x4 acc = {0.f, 0.f, 0.f, 0.f};

  for (int i = 0; i < I_IMG; ++i) {
    __syncthreads();   // zeros visible / prior Ald reads + rp reads done
    for (int idx = tid; idx < NPIX; idx += 256) {
      int y = idx / OW, x = idx - y * OW;
      rp[(y + 1) * RPW + (x + 1)] = r[(size_t)(i * S_SEQ + s) * NPIX + idx];
    }
    __syncthreads();
    for (int idx = tid; idx < 16 * BPL; idx += 256) {
      int t = idx / BPL, pp = idx - t * BPL;
      ushort val = 0;
      if (pp < HW) {
        int u = pp / 18, vv = pp - u * 18;
        int dy = t >> 2, dx = t & 3;
        val = bf16r(rp[(u + 3 - dy) * RPW + (vv + 3 - dx)]);
      }
      Ald[t * ASTR + pp] = val;
    }
    __syncthreads();

    const ushort* arow = Ald + nsub * ASTR + kg * 8;
    s16x8 afr[11];
    #pragma unroll
    for (int ks = 0; ks < 11; ++ks)
      afr[ks] = *(const s16x8*)(arow + ks * 32);

    const float* fb = feat + ((size_t)(i * S_SEQ + s) * C_CH + c) * HW + kg * 8;
    #pragma unroll
    for (int ks = 0; ks < 10; ++ks) {
      float4 x = *(const float4*)(fb + ks * 32);
      float4 y = *(const float4*)(fb + ks * 32 + 4);
      u32x4 t = {cvtpk(x.x, x.y), cvtpk(x.z, x.w),
                 cvtpk(y.x, y.y), cvtpk(y.z, y.w)};
      s16x8 bf = __builtin_bit_cast(s16x8, t);
      acc = __builtin_amdgcn_mfma_f32_16x16x32_bf16(afr[ks], bf, acc, 0, 0, 0);
    }
    {
      s16x8 bf = {0, 0, 0, 0, 0, 0, 0, 0};
      if (kg == 0) {
        float4 x = *(const float4*)(fb + 320);
        u32x4 t = {cvtpk(x.x, x.y), cvtpk(x.z, x.w), 0u, 0u};
        bf = __builtin_bit_cast(s16x8, t);
      }
      acc = __builtin_amdgcn_mfma_f32_16x16x32_bf16(afr[10], bf, acc, 0, 0, 0);
    }
  }

  // epilogue (fused combine_wg): lane owns taps kg*4..+3 of channel c
  size_t widx = ((size_t)s * C_CH + c) * FT + kg * 4;
  float4 wv4 = *(const float4*)(wcur + widx);
  float4 out;
  out.x = acc[0] + regv * wv4.x;
  out.y = acc[1] + regv * wv4.y;
  out.z = acc[2] + regv * wv4.z;
  out.w = acc[3] + regv * wv4.w;
  *(float4*)(wg + widx) = out;
  ushort* wb = wTb + (size_t)s * 16 * 512;
  wb[(kg * 4 + 0) * 512 + c] = bf16r(out.x);
  wb[(kg * 4 + 1) * 512 + c] = bf16r(out.y);
  wb[(kg * 4 + 2) * 512 + c] = bf16r(out.z);
  wb[(kg * 4 + 3) * 512 + c] = bf16r(out.w);
  float sq = out.x * out.x + out.y * out.y + out.z * out.z + out.w * out.w;
  float tot = blk_reduce(sq, rtmp);
  if (tid == 0) numpp[s * 8 + cb] = tot;
}

// ---------------------------------------------------------------------------
// gather scores from S planes
// ---------------------------------------------------------------------------
__device__ inline float s_gather(const float* __restrict__ Sp, int yo, int xo) {
  float sv = 0.f;
  #pragma unroll
  for (int dy = 0; dy < 4; ++dy) {
    int yi = yo + dy - 2;
    if (yi < 0 || yi >= H_IN) continue;
    #pragma unroll
    for (int dx = 0; dx < 4; ++dx) {
      int xi = xo + dx - 2;
      if (xi < 0 || xi >= W_IN) continue;
      sv += Sp[(dy * 4 + dx) * SPL + yi * W_IN + xi];
    }
  }
  return sv;
}

// ---------------------------------------------------------------------------
// combine0 (once): S -> scores + mask + residuals
// ---------------------------------------------------------------------------
__global__ __launch_bounds__(384) void combine0_k(
    const float* __restrict__ S,
    const float* __restrict__ sw, const float* __restrict__ lm,
    const float* __restrict__ alo, const float* __restrict__ ahi,
    float* __restrict__ scores,
    float* __restrict__ mask, float* __restrict__ rbuf)
{
  int n = blockIdx.x;
  int p = threadIdx.x;
  if (p >= NPIX) return;
  int yo = p / OW, xo = p - yo * OW;
  float sv = s_gather(S + (size_t)n * 16 * SPL, yo, xo);
  int idx = n * NPIX + p;
  scores[idx] = sv;
  float lo = alo[idx], hi = ahi[idx], s_w = sw[idx], l_v = lm[idx];
  float sgn = (sv > 0.f) ? 1.f : ((sv < 0.f) ? -1.f : 0.f);
  float actv = lo * fabsf(sv) + hi * sv;
  float msk = lo * sgn + hi;
  mask[idx] = msk;
  rbuf[idx] = msk * s_w * s_w * (actv - l_v);
}

// ---------------------------------------------------------------------------
// update (1024 threads): den from S-gathered sg, num from 8 partials,
// alpha, weight step, incremental scores, next mask/residuals.
// ---------------------------------------------------------------------------
__global__ __launch_bounds__(1024) void update_k(
    float* __restrict__ wcur, const float* __restrict__ wg,
    const float* __restrict__ S,
    const float* __restrict__ sw, const float* __restrict__ lm,
    const float* __restrict__ alo, const float* __restrict__ ahi,
    float* __restrict__ scores, float* __restrict__ mask,
    float* __restrict__ rbuf,
    const float* __restrict__ numpp, const float* __restrict__ scal)
{
  __shared__ float rtmp[16];
  __shared__ float s_sa;
  int s = blockIdx.x;
  int tid = threadIdx.x;

  float sgl[2];
  float sq = 0.f;
  #pragma unroll
  for (int k = 0; k < 2; ++k) {
    int g = tid + k * 1024;
    sgl[k] = 0.f;
    if (g < I_IMG * NPIX) {
      int i = g / NPIX, p = g - i * NPIX;
      int n = i * S_SEQ + s;
      int yo = p / OW, xo = p - yo * OW;
      float sv = s_gather(S + (size_t)n * 16 * SPL, yo, xo);
      sgl[k] = sv;
      int idx = n * NPIX + p;
      float sg = sw[idx] * mask[idx] * sv;
      sq += sg * sg;
    }
  }
  float den = blk_reduce(sq, rtmp);
  if (tid == 0) {
    float num = 0.f;
    #pragma unroll
    for (int k = 0; k < 8; ++k) num += numpp[s * 8 + k];
    float regv = scal[1], step = scal[0];
    float d = fmaxf(den + regv * num, 1e-8f);
    s_sa = step * (num / d);
  }
  __syncthreads();
  float sa = s_sa;

  float4* w4 = (float4*)(wcur + (size_t)s * (C_CH * FT));
  const float4* g4 = (const float4*)(wg + (size_t)s * (C_CH * FT));
  for (int idx = tid; idx < C_CH * FT / 4; idx += 1024) {
    float4 w = w4[idx], g = g4[idx];
    w.x -= sa * g.x; w.y -= sa * g.y; w.z -= sa * g.z; w.w -= sa * g.w;
    w4[idx] = w;
  }

  #pragma unroll
  for (int k = 0; k < 2; ++k) {
    int g = tid + k * 1024;
    if (g < I_IMG * NPIX) {
      int i = g / NPIX, p = g - i * NPIX;
      int idx = (i * S_SEQ + s) * NPIX + p;
      float sv = scores[idx] - sa * sgl[k];
      scores[idx] = sv;
      float lo = alo[idx], hi = ahi[idx], s_w = sw[idx], l_v = lm[idx];
      float sgn = (sv > 0.f) ? 1.f : ((sv < 0.f) ? -1.f : 0.f);
      float actv = lo * fabsf(sv) + hi * sv;
      float msk = lo * sgn + hi;
      mask[idx] = msk;
      rbuf[idx] = msk * s_w * s_w * (actv - l_v);
    }
  }
}

// ---------------------------------------------------------------------------
extern "C" void kernel_launch(void* const* d_in, const int* in_sizes, int n_in,
                              void* d_out, int out_size, void* d_ws, size_t ws_size,
                              hipStream_t stream)
{
  const float* w_in = (const float*)d_in[0];
  const float* feat = (const float*)d_in[1];
  const float* bb   = (const float*)d_in[2];
  const float* lblw = (const float*)d_in[3];
  const float* mskw = (const float*)d_in[4];
  const float* spw  = (const float*)d_in[5];
  const float* lsl  = (const float*)d_in[6];
  const float* freg = (const float*)d_in[7];

  float* base = (float*)d_ws;
  const int NMAP = I_IMG * S_SEQ * NPIX;   // 69312
  const int NW   = S_SEQ * C_CH * FT;      // 524288
  float* sw     = base;
  float* lm     = sw + NMAP;
  float* alo    = lm + NMAP;
  float* ahi    = alo + NMAP;
  float* mask   = ahi + NMAP;
  float* rbuf   = mask + NMAP;
  float* scores = rbuf + NMAP;
  float* wcur   = scores + NMAP;
  float* wg     = wcur + NW;
  float* numpp  = wg + NW;                 // S_SEQ*8
  float* scal   = numpp + S_SEQ * 8;
  float* Sbuf   = scal + 8;                // 192*16*336
  ushort* wTb   = (ushort*)(Sbuf + (size_t)I_IMG * S_SEQ * 16 * SPL);
  ushort* featT = wTb + (size_t)S_SEQ * 16 * 512;

  convert_k<<<dim3(I_IMG * S_SEQ, 24), 256, 0, stream>>>(feat, featT);
  prep_k<<<I_IMG * S_SEQ, 384, 0, stream>>>(bb, lblw, mskw, spw, lsl, freg,
                                            sw, lm, alo, ahi, scal);
  hipMemcpyAsync(wcur, w_in, (size_t)NW * sizeof(float),
                 hipMemcpyDeviceToDevice, stream);

  // initial scores via MFMA GEMM
  wT_k<<<S_SEQ, 256, 0, stream>>>(wcur, wTb);
  mfma_fwd_k<<<dim3(I_IMG * S_SEQ, 6), 256, 0, stream>>>(featT, wTb, Sbuf);
  combine0_k<<<I_IMG * S_SEQ, 384, 0, stream>>>(
      Sbuf, sw, lm, alo, ahi, scores, mask, rbuf);

  for (int it = 0; it < NITER; ++it) {
    mfma_tr_k<<<dim3(8, S_SEQ), 256, 0, stream>>>(
        feat, rbuf, wcur, scal, wg, wTb, numpp);
    mfma_fwd_k<<<dim3(I_IMG * S_SEQ, 6), 256, 0, stream>>>(featT, wTb, Sbuf);
    update_k<<<S_SEQ, 1024, 0, stream>>>(
        wcur, wg, Sbuf, sw, lm, alo, ahi, scores, mask, rbuf, numpp, scal);
  }
  hipMemcpyAsync(d_out, wcur, (size_t)NW * sizeof(float),
                 hipMemcpyDeviceToDevice, stream);
}